// Round 7
// baseline (287.726 us; speedup 1.0000x reference)
//
#include <hip/hip_runtime.h>
#include <math.h>

#define B_ 2
#define S_ 2048
#define C_ 1024
#define H_ 16
#define D_ 64

typedef __bf16 bf16_t;
typedef __attribute__((ext_vector_type(8))) __bf16 bf16x8;
typedef __attribute__((ext_vector_type(4))) __bf16 bf16x4;
typedef __attribute__((ext_vector_type(4))) float f32x4;

__device__ __forceinline__ void gload16(const void* g, void* l) {
    __builtin_amdgcn_global_load_lds(
        (const __attribute__((address_space(1))) unsigned int*)g,
        (__attribute__((address_space(3))) unsigned int*)l, 16, 0, 0);
}

__device__ __forceinline__ float tanh_fast(float z) {
    z = fminf(fmaxf(z, -12.f), 12.f);
    float e = __expf(2.f * z);
    return 1.f - __fdividef(2.f, e + 1.f);
}

__device__ __forceinline__ float mish_f(float x) {
    float sp = (x > 15.f) ? x : log1pf(__expf(x));
    return x * tanh_fast(sp);
}

// tanh(t*w+b) with 2/ln2 pre-folded into w2,b2: 1 - 2*rcp(exp2(t*w2+b2)+1)
__device__ __forceinline__ float tanh_folded(float t, float w2, float b2) {
    float e = __builtin_amdgcn_exp2f(fmaf(t, w2, b2));
    float r = __builtin_amdgcn_rcpf(e + 1.f);
    return fmaf(-2.f, r, 1.f);
}

// -------------------------------------------------------------------------
// Merged preprocessing: blocks 0..4095 = fp32->bf16 of y,x;
// blocks 4096..4863 = transpose-convert wq/wk/wv -> [N][K] bf16;
// blocks 4864..4871 = zero Mm (replaces hipMemsetAsync dispatch).
// -------------------------------------------------------------------------
__global__ __launch_bounds__(256) void prep_kernel(
    const float* __restrict__ y, bf16_t* __restrict__ ybf,
    const float* __restrict__ x, bf16_t* __restrict__ xbf,
    const float* __restrict__ wq, const float* __restrict__ wk,
    const float* __restrict__ wv,
    bf16_t* __restrict__ wqt, bf16_t* __restrict__ wkt,
    bf16_t* __restrict__ wvt, float* __restrict__ Mm)
{
    __shared__ float ts[64][65];
    const int bid = blockIdx.x;
    const int t = threadIdx.x;
    if (bid < 4096) {
        const float* in = (bid < 2048) ? y : x;
        bf16_t* out = (bid < 2048) ? ybf : xbf;
        size_t i = ((size_t)(bid & 2047) * 256 + t) * 8;
        float4 u = *(const float4*)&in[i];
        float4 v = *(const float4*)&in[i + 4];
        bf16x8 o;
        o[0] = (bf16_t)u.x; o[1] = (bf16_t)u.y; o[2] = (bf16_t)u.z; o[3] = (bf16_t)u.w;
        o[4] = (bf16_t)v.x; o[5] = (bf16_t)v.y; o[6] = (bf16_t)v.z; o[7] = (bf16_t)v.w;
        *(bf16x8*)&out[i] = o;
    } else if (bid < 4864) {
        const int r3 = bid - 4096;           // 0..767
        const int z = r3 >> 8;
        const int rem = r3 & 255;
        const int k0 = (rem >> 4) * 64, n0 = (rem & 15) * 64;
        const float* in = z == 0 ? wq : (z == 1 ? wk : wv);
        bf16_t* out = z == 0 ? wqt : (z == 1 ? wkt : wvt);
        const int r = t >> 2, c0 = (t & 3) * 16;
        #pragma unroll
        for (int j = 0; j < 16; j += 4) {
            float4 v = *(const float4*)&in[(size_t)(k0 + r) * C_ + n0 + c0 + j];
            ts[c0 + j + 0][r] = v.x; ts[c0 + j + 1][r] = v.y;
            ts[c0 + j + 2][r] = v.z; ts[c0 + j + 3][r] = v.w;
        }
        __syncthreads();
        #pragma unroll
        for (int g = 0; g < 2; ++g) {
            bf16x8 o;
            #pragma unroll
            for (int e = 0; e < 8; ++e) o[e] = (bf16_t)ts[r][c0 + g * 8 + e];
            *(bf16x8*)&out[(size_t)(n0 + r) * C_ + k0 + c0 + g * 8] = o;
        }
    } else {
        // zero Mm: 131072 floats over 8 blocks, 64 floats/thread
        float* p = Mm + (size_t)(bid - 4864) * 16384 + (size_t)t * 64;
        float4 z4 = {0.f, 0.f, 0.f, 0.f};
        #pragma unroll
        for (int k = 0; k < 64; k += 4) *(float4*)&p[k] = z4;
    }
}

// -------------------------------------------------------------------------
// Fused QKV projection. z=0: y@wq -> Qt (transposed), z=1: x@wk -> Kb,
// z=2: y@wv -> Vt (transposed). 128x128 tile, BK=32.
// Epilogue: LDS round-trip so ALL global stores are coalesced bf16x8 rows
// (direct transposed stores were 8 B scattered at 4 KB stride).
// -------------------------------------------------------------------------
__global__ __launch_bounds__(256) void qkv_proj(
    const bf16_t* __restrict__ ybf, const bf16_t* __restrict__ xbf,
    const bf16_t* __restrict__ wqt, const bf16_t* __restrict__ wkt,
    const bf16_t* __restrict__ wvt,
    const float* __restrict__ bq, const float* __restrict__ bk,
    const float* __restrict__ bv,
    bf16_t* __restrict__ Qt, bf16_t* __restrict__ Kb, bf16_t* __restrict__ Vt)
{
    const int z = blockIdx.z;
    const bf16_t* A  = (z == 1) ? xbf : ybf;
    const bf16_t* Bt = (z == 0) ? wqt : (z == 1) ? wkt : wvt;
    const float* bias = (z == 0) ? bq : (z == 1) ? bk : bv;
    const int K = C_;

    __shared__ bf16_t smem[128 * 136];   // 34 KB; staging + epilogue tile
    bf16_t* As = smem;                   // 128*32
    bf16_t* Bs = smem + 4096;            // 128*32

    const int t = threadIdx.x;
    const int w = t >> 6, lane = t & 63;
    const int wm = (w >> 1) * 64, wn = (w & 1) * 64;
    const int l15 = lane & 15, l4 = lane >> 4;
    const int row0 = blockIdx.y * 128, col0 = blockIdx.x * 128;

    const int sr = t >> 2, sk = (t & 3) * 8;
    const bf16_t* gA = A + (size_t)(row0 + sr) * K + sk;
    const bf16_t* gB = Bt + (size_t)(col0 + sr) * K + sk;
    bf16_t* lA = As + (t & ~63) * 8;
    bf16_t* lB = Bs + (t & ~63) * 8;

    f32x4 acc[4][4] = {};

    for (int k0 = 0; k0 < K; k0 += 32) {
        __syncthreads();
        gload16(gA + k0, lA);
        gload16(gA + k0 + (size_t)64 * K, lA + 2048);
        gload16(gB + k0, lB);
        gload16(gB + k0 + (size_t)64 * K, lB + 2048);
        __syncthreads();
        bf16x8 a[4], b[4];
        #pragma unroll
        for (int i = 0; i < 4; ++i)
            a[i] = *(const bf16x8*)&As[(wm + i * 16 + l15) * 32 + l4 * 8];
        #pragma unroll
        for (int j = 0; j < 4; ++j)
            b[j] = *(const bf16x8*)&Bs[(wn + j * 16 + l15) * 32 + l4 * 8];
        #pragma unroll
        for (int i = 0; i < 4; ++i)
            #pragma unroll
            for (int j = 0; j < 4; ++j)
                acc[i][j] = __builtin_amdgcn_mfma_f32_16x16x32_bf16(
                    a[i], b[j], acc[i][j], 0, 0, 0);
    }

    // ---- epilogue: bias + (optional transpose) via LDS, coalesced stores
    __syncthreads();   // all waves done reading As/Bs
    if (z != 1) {
        // T[n][m] (transposed): bf16x4 contiguous in m
        #pragma unroll
        for (int i = 0; i < 4; ++i)
            #pragma unroll
            for (int j = 0; j < 4; ++j) {
                int n = wn + j * 16 + l15;
                float bv2 = bias[col0 + n];
                bf16x4 o;
                #pragma unroll
                for (int r = 0; r < 4; ++r) o[r] = (bf16_t)(acc[i][j][r] + bv2);
                *(bf16x4*)&smem[(size_t)n * 136 + wm + i * 16 + l4 * 4] = o;
            }
    } else {
        // T[m][n]: scalar writes (m varies within acc quad)
        #pragma unroll
        for (int i = 0; i < 4; ++i)
            #pragma unroll
            for (int j = 0; j < 4; ++j) {
                int n = wn + j * 16 + l15;
                float bv2 = bias[col0 + n];
                #pragma unroll
                for (int r = 0; r < 4; ++r)
                    smem[(size_t)(wm + i * 16 + l4 * 4 + r) * 136 + n] =
                        (bf16_t)(acc[i][j][r] + bv2);
            }
    }
    __syncthreads();

    const int r0 = t >> 1, half = t & 1;
    const bf16_t* src = &smem[(size_t)r0 * 136 + half * 64];
    if (z != 1) {
        bf16_t* To = (z == 0) ? Qt : Vt;
        const int b2 = row0 >> 11, sbase = (row0 & 2047) + half * 64;
        bf16_t* dst = &To[((size_t)b2 * C_ + col0 + r0) * S_ + sbase];
        #pragma unroll
        for (int k = 0; k < 64; k += 8)
            *(bf16x8*)&dst[k] = *(const bf16x8*)&src[k];
    } else {
        bf16_t* dst = &Kb[(size_t)(row0 + r0) * C_ + col0 + half * 64];
        #pragma unroll
        for (int k = 0; k < 64; k += 8)
            *(bf16x8*)&dst[k] = *(const bf16x8*)&src[k];
    }
}

// -------------------------------------------------------------------------
// FUSED cv + qtcv (R5 structure — best measured):
//   As (tanh tiles) wave-private (no barrier); Bs double-buffered;
//   single __syncthreads per iter; t_mat register prefetch one iter deep.
// grid (S/128=16, P=4, BH=32) = 2048 blocks, 8 blocks/CU (20 KB LDS).
// -------------------------------------------------------------------------
__global__ __launch_bounds__(256) void cv_qtcv_fused(
    const float* __restrict__ t_mat, const bf16_t* __restrict__ Vt,
    const bf16_t* __restrict__ Qt,
    const float* __restrict__ wc, const float* __restrict__ bc,
    float* __restrict__ Mm)
{
    const int bh = blockIdx.z, b = bh >> 4, h = bh & 15;
    const int q0 = blockIdx.x * 128;
    const int p = blockIdx.y;
    const int t = threadIdx.x;
    const int w = t >> 6, lane = t & 63;
    const int l15 = lane & 15, l4 = lane >> 4;

    __shared__ bf16_t smem[10240];       // 20 KB
    bf16_t* As = smem;                   // 128*32 (8 KB)
    bf16_t* Bs = smem + 4096;            // 2 x 64*32 (8 KB)
    bf16_t* cvs = smem;                  // epilogue: [c][64][40]

    const float LOG2E2 = 2.8853900817779268f;  // 2/ln2
    const float wch2 = wc[h] * LOG2E2, bch2 = bc[h] * LOG2E2;
    const float* tb = t_mat + (size_t)b * S_ * S_ + (size_t)q0 * S_;
    const bf16_t* Vb = Vt + ((size_t)b * C_ + h * 64) * S_;

    const int rr = t >> 1, sp = (t & 1) * 16;
    const int vd = t >> 2, vse = (t & 3) * 8;
    const int lBoff = (t & ~63) * 8;

    f32x4 acc[2][4] = {};

    const int s_beg = p * 512, s_end = s_beg + 512;
    const float* trow = tb + (size_t)rr * S_ + sp;

    float4 v0 = *(const float4*)&trow[s_beg];
    float4 v1 = *(const float4*)&trow[s_beg + 4];
    float4 v2 = *(const float4*)&trow[s_beg + 8];
    float4 v3 = *(const float4*)&trow[s_beg + 12];

    int buf = 0;
    for (int s0 = s_beg; s0 < s_end; s0 += 32, buf ^= 1) {
        bf16x8 p0, p1;
        p0[0] = (bf16_t)tanh_folded(v0.x, wch2, bch2);
        p0[1] = (bf16_t)tanh_folded(v0.y, wch2, bch2);
        p0[2] = (bf16_t)tanh_folded(v0.z, wch2, bch2);
        p0[3] = (bf16_t)tanh_folded(v0.w, wch2, bch2);
        p0[4] = (bf16_t)tanh_folded(v1.x, wch2, bch2);
        p0[5] = (bf16_t)tanh_folded(v1.y, wch2, bch2);
        p0[6] = (bf16_t)tanh_folded(v1.z, wch2, bch2);
        p0[7] = (bf16_t)tanh_folded(v1.w, wch2, bch2);
        p1[0] = (bf16_t)tanh_folded(v2.x, wch2, bch2);
        p1[1] = (bf16_t)tanh_folded(v2.y, wch2, bch2);
        p1[2] = (bf16_t)tanh_folded(v2.z, wch2, bch2);
        p1[3] = (bf16_t)tanh_folded(v2.w, wch2, bch2);
        p1[4] = (bf16_t)tanh_folded(v3.x, wch2, bch2);
        p1[5] = (bf16_t)tanh_folded(v3.y, wch2, bch2);
        p1[6] = (bf16_t)tanh_folded(v3.z, wch2, bch2);
        p1[7] = (bf16_t)tanh_folded(v3.w, wch2, bch2);
        gload16(Vb + (size_t)vd * S_ + s0 + vse, Bs + buf * 2048 + lBoff);
        *(bf16x8*)&As[rr * 32 + sp] = p0;
        *(bf16x8*)&As[rr * 32 + sp + 8] = p1;
        __syncthreads();
        if (s0 + 32 < s_end) {
            const float* nrow = &trow[s0 + 32];
            v0 = *(const float4*)&nrow[0];
            v1 = *(const float4*)&nrow[4];
            v2 = *(const float4*)&nrow[8];
            v3 = *(const float4*)&nrow[12];
        }
        bf16x8 a0 = *(const bf16x8*)&As[(w * 32 + l15) * 32 + l4 * 8];
        bf16x8 a1 = *(const bf16x8*)&As[(w * 32 + 16 + l15) * 32 + l4 * 8];
        #pragma unroll
        for (int j = 0; j < 4; ++j) {
            bf16x8 bb = *(const bf16x8*)&Bs[buf * 2048 + (j * 16 + l15) * 32 + l4 * 8];
            acc[0][j] = __builtin_amdgcn_mfma_f32_16x16x32_bf16(a0, bb, acc[0][j], 0, 0, 0);
            acc[1][j] = __builtin_amdgcn_mfma_f32_16x16x32_bf16(a1, bb, acc[1][j], 0, 0, 0);
        }
    }

    // ---- epilogue: M[d',d] += Qt[d',q] * cv(q,d) over this block's q-tile
    __syncthreads();
    #pragma unroll
    for (int i = 0; i < 2; ++i)
        #pragma unroll
        for (int j = 0; j < 4; ++j) {
            int d = j * 16 + l15;
            bf16x4 o;
            #pragma unroll
            for (int r = 0; r < 4; ++r) o[r] = (bf16_t)acc[i][j][r];
            *(bf16x4*)&cvs[(size_t)w * 2560 + d * 40 + i * 16 + l4 * 4] = o;
        }
    __syncthreads();

    const bf16_t* Qrow = Qt + ((size_t)b * C_ + h * 64 + w * 16 + l15) * S_ + q0 + l4 * 8;
    f32x4 macc[4] = {};
    #pragma unroll
    for (int c = 0; c < 4; ++c) {
        bf16x8 a = *(const bf16x8*)&Qrow[c * 32];
        #pragma unroll
        for (int j = 0; j < 4; ++j) {
            bf16x8 bb = *(const bf16x8*)&cvs[(size_t)c * 2560 + (j * 16 + l15) * 40 + l4 * 8];
            macc[j] = __builtin_amdgcn_mfma_f32_16x16x32_bf16(a, bb, macc[j], 0, 0, 0);
        }
    }

    float* mp = Mm + (size_t)bh * 64 * 64;
    #pragma unroll
    for (int j = 0; j < 4; ++j)
        #pragma unroll
        for (int r = 0; r < 4; ++r)
            atomicAdd(&mp[(size_t)(w * 16 + l4 * 4 + r) * 64 + j * 16 + l15],
                      macc[j][r]);
}

// -------------------------------------------------------------------------
// Wefft[b, co, h*64+d'] = (1/8) * sum_d M[bh,d',d] * wf[h*64+d, co]  (bf16)
// -------------------------------------------------------------------------
__global__ __launch_bounds__(256) void weff_kernel(
    const float* __restrict__ Mm, const float* __restrict__ wf,
    bf16_t* __restrict__ Wefft)
{
    const int b = blockIdx.z, h = blockIdx.y;
    const int co0 = blockIdx.x * 64;
    const int t = threadIdx.x;
    const int tx = t & 15, ty = t >> 4;

    __shared__ float Ms[64][64];
    __shared__ float Ws[64][64];

    const float* Mb = Mm + (size_t)(b * H_ + h) * 64 * 64;

    const int r  = t >> 2;
    const int c4 = (t & 3) << 2;

    #pragma unroll
    for (int rep = 0; rep < 4; ++rep) {
        int col = c4 + rep * 16;
        float4 m4 = *(const float4*)&Mb[(size_t)r * 64 + col];
        Ms[col + 0][r] = m4.x; Ms[col + 1][r] = m4.y;
        Ms[col + 2][r] = m4.z; Ms[col + 3][r] = m4.w;
        float4 w4 = *(const float4*)&wf[(size_t)(h * 64 + r) * C_ + co0 + col];
        *(float4*)&Ws[r][col] = w4;
    }
    __syncthreads();

    float acc[4][4] = {};
    #pragma unroll
    for (int kk = 0; kk < 64; ++kk) {
        float av[4], bv2[4];
        *(float4*)&av[0] = *(const float4*)&Ms[kk][ty * 4];
        *(float4*)&bv2[0] = *(const float4*)&Ws[kk][tx * 4];
        #pragma unroll
        for (int i = 0; i < 4; ++i)
            #pragma unroll
            for (int j = 0; j < 4; ++j)
                acc[i][j] = fmaf(av[i], bv2[j], acc[i][j]);
    }

    bf16_t* wp = Wefft + (size_t)b * C_ * C_;
    #pragma unroll
    for (int i = 0; i < 4; ++i)
        #pragma unroll
        for (int j = 0; j < 4; ++j)
            wp[(size_t)(co0 + tx * 4 + j) * C_ + h * 64 + ty * 4 + i] =
                (bf16_t)(acc[i][j] * 0.125f);  // fold 1/sqrt(D)=1/8
}

// -------------------------------------------------------------------------
// out = mish(Kb[b] @ Wefft[b]^T + bf), fp32 out. 128x64 tiles,
// grid (16, 16, 2) = 512 blocks (2/CU).
// -------------------------------------------------------------------------
__global__ __launch_bounds__(256) void final_gemm(
    const bf16_t* __restrict__ Kb, const bf16_t* __restrict__ Weft,
    const float* __restrict__ bias, float* __restrict__ out)
{
    const int z = blockIdx.z;
    const bf16_t* A  = Kb + (size_t)z * S_ * C_;
    const bf16_t* Bt = Weft + (size_t)z * C_ * C_;
    float* Co = out + (size_t)z * S_ * C_;
    const int K = C_;

    __shared__ bf16_t As[128 * 32];
    __shared__ bf16_t Bs[64 * 32];

    const int t = threadIdx.x;
    const int w = t >> 6, lane = t & 63;
    const int l15 = lane & 15, l4 = lane >> 4;
    const int row0 = blockIdx.y * 128, col0 = blockIdx.x * 64;

    const int sr = t >> 2, sk = (t & 3) * 8;
    const bf16_t* gA = A + (size_t)(row0 + sr) * K + sk;
    const bf16_t* gB = Bt + (size_t)(col0 + sr) * K + sk;
    bf16_t* lA = As + (t & ~63) * 8;
    bf16_t* lB = Bs + (t & ~63) * 8;

    f32x4 acc[2][4] = {};

    for (int k0 = 0; k0 < K; k0 += 32) {
        __syncthreads();
        gload16(gA + k0, lA);
        gload16(gA + k0 + (size_t)64 * K, lA + 2048);
        gload16(gB + k0, lB);
        __syncthreads();
        bf16x8 a0 = *(const bf16x8*)&As[(w * 32 + l15) * 32 + l4 * 8];
        bf16x8 a1 = *(const bf16x8*)&As[(w * 32 + 16 + l15) * 32 + l4 * 8];
        #pragma unroll
        for (int j = 0; j < 4; ++j) {
            bf16x8 bb = *(const bf16x8*)&Bs[(j * 16 + l15) * 32 + l4 * 8];
            acc[0][j] = __builtin_amdgcn_mfma_f32_16x16x32_bf16(a0, bb, acc[0][j], 0, 0, 0);
            acc[1][j] = __builtin_amdgcn_mfma_f32_16x16x32_bf16(a1, bb, acc[1][j], 0, 0, 0);
        }
    }

    #pragma unroll
    for (int i = 0; i < 2; ++i)
        #pragma unroll
        for (int j = 0; j < 4; ++j) {
            int c = col0 + j * 16 + l15;
            float bv2 = bias[c];
            #pragma unroll
            for (int r = 0; r < 4; ++r) {
                int m = row0 + w * 32 + i * 16 + l4 * 4 + r;
                Co[(size_t)m * C_ + c] = mish_f(acc[i][j][r] + bv2);
            }
        }
}

// -------------------------------------------------------------------------
extern "C" void kernel_launch(void* const* d_in, const int* in_sizes, int n_in,
                              void* d_out, int out_size, void* d_ws, size_t ws_size,
                              hipStream_t stream) {
    const float* x     = (const float*)d_in[0];
    const float* y     = (const float*)d_in[1];
    const float* t_mat = (const float*)d_in[2];
    const float* wq    = (const float*)d_in[3];
    const float* bq    = (const float*)d_in[4];
    const float* wk    = (const float*)d_in[5];
    const float* bk    = (const float*)d_in[6];
    const float* wv    = (const float*)d_in[7];
    const float* bv    = (const float*)d_in[8];
    const float* wc    = (const float*)d_in[9];
    const float* bc    = (const float*)d_in[10];
    const float* wf    = (const float*)d_in[11];
    const float* bf    = (const float*)d_in[12];
    float* out = (float*)d_out;

    // workspace layout (byte offsets)
    char* base = (char*)d_ws;
    bf16_t* Qt   = (bf16_t*)(base + 0);          //  8 MiB  [b][c][s]
    bf16_t* Kb   = (bf16_t*)(base + 8388608);    //  8 MiB  [b*s][c]
    bf16_t* Vt   = (bf16_t*)(base + 16777216);   //  8 MiB  [b][c][s]
    float*  Mm   = (float*) (base + 25165824);   //  0.5 MiB
    bf16_t* Weft = (bf16_t*)(base + 25690112);   //  4 MiB  [b][co][cin]
    bf16_t* ybf  = (bf16_t*)(base + 29884416);   //  8 MiB
    bf16_t* xbf  = (bf16_t*)(base + 38273024);   //  8 MiB
    bf16_t* wqt  = (bf16_t*)(base + 46661632);   //  2 MiB
    bf16_t* wkt  = (bf16_t*)(base + 48758784);   //  2 MiB
    bf16_t* wvt  = (bf16_t*)(base + 50855936);   //  2 MiB

    dim3 blk(256);

    // merged conversions + weight transposes + Mm zeroing (4872 blocks)
    prep_kernel<<<dim3(4872), blk, 0, stream>>>(
        y, ybf, x, xbf, wq, wk, wv, wqt, wkt, wvt, Mm);

    // fused QKV projections (768 blocks), coalesced epilogue
    qkv_proj<<<dim3(C_ / 128, (B_ * S_) / 128, 3), blk, 0, stream>>>(
        ybf, xbf, wqt, wkt, wvt, bq, bk, bv, Qt, Kb, Vt);

    // fused cv + M-accumulation (2048 blocks)
    cv_qtcv_fused<<<dim3(S_ / 128, 4, B_ * H_), blk, 0, stream>>>(
        t_mat, Vt, Qt, wc, bc, Mm);

    // Weff^T (bf16), 1/8 folded
    weff_kernel<<<dim3(C_ / 64, H_, B_), blk, 0, stream>>>(Mm, wf, Weft);

    // out = mish(K @ Weff + bf), 512 blocks
    final_gemm<<<dim3(C_ / 64, S_ / 128, B_), blk, 0, stream>>>(
        Kb, Weft, bf, out);
}

// Round 8
// 279.826 us; speedup vs baseline: 1.0282x; 1.0282x over previous
//
#include <hip/hip_runtime.h>
#include <math.h>

#define B_ 2
#define S_ 2048
#define C_ 1024
#define H_ 16
#define D_ 64

typedef __bf16 bf16_t;
typedef __attribute__((ext_vector_type(8))) __bf16 bf16x8;
typedef __attribute__((ext_vector_type(4))) __bf16 bf16x4;
typedef __attribute__((ext_vector_type(4))) float f32x4;

__device__ __forceinline__ void gload16(const void* g, void* l) {
    __builtin_amdgcn_global_load_lds(
        (const __attribute__((address_space(1))) unsigned int*)g,
        (__attribute__((address_space(3))) unsigned int*)l, 16, 0, 0);
}

__device__ __forceinline__ float tanh_fast(float z) {
    z = fminf(fmaxf(z, -12.f), 12.f);
    float e = __expf(2.f * z);
    return 1.f - __fdividef(2.f, e + 1.f);
}

__device__ __forceinline__ float mish_f(float x) {
    float sp = (x > 15.f) ? x : log1pf(__expf(x));
    return x * tanh_fast(sp);
}

// tanh(t*w+b) with 2/ln2 pre-folded into w2,b2: 1 - 2*rcp(exp2(t*w2+b2)+1)
__device__ __forceinline__ float tanh_folded(float t, float w2, float b2) {
    float e = __builtin_amdgcn_exp2f(fmaf(t, w2, b2));
    float r = __builtin_amdgcn_rcpf(e + 1.f);
    return fmaf(-2.f, r, 1.f);
}

// -------------------------------------------------------------------------
// Merged preprocessing: blocks 0..4095 = fp32->bf16 of y,x;
// blocks 4096..4863 = transpose-convert wq/wk/wv -> [N][K] bf16;
// blocks 4864..4871 = zero Mm (replaces hipMemsetAsync dispatch).
// -------------------------------------------------------------------------
__global__ __launch_bounds__(256) void prep_kernel(
    const float* __restrict__ y, bf16_t* __restrict__ ybf,
    const float* __restrict__ x, bf16_t* __restrict__ xbf,
    const float* __restrict__ wq, const float* __restrict__ wk,
    const float* __restrict__ wv,
    bf16_t* __restrict__ wqt, bf16_t* __restrict__ wkt,
    bf16_t* __restrict__ wvt, float* __restrict__ Mm)
{
    __shared__ float ts[64][65];
    const int bid = blockIdx.x;
    const int t = threadIdx.x;
    if (bid < 4096) {
        const float* in = (bid < 2048) ? y : x;
        bf16_t* out = (bid < 2048) ? ybf : xbf;
        size_t i = ((size_t)(bid & 2047) * 256 + t) * 8;
        float4 u = *(const float4*)&in[i];
        float4 v = *(const float4*)&in[i + 4];
        bf16x8 o;
        o[0] = (bf16_t)u.x; o[1] = (bf16_t)u.y; o[2] = (bf16_t)u.z; o[3] = (bf16_t)u.w;
        o[4] = (bf16_t)v.x; o[5] = (bf16_t)v.y; o[6] = (bf16_t)v.z; o[7] = (bf16_t)v.w;
        *(bf16x8*)&out[i] = o;
    } else if (bid < 4864) {
        const int r3 = bid - 4096;           // 0..767
        const int z = r3 >> 8;
        const int rem = r3 & 255;
        const int k0 = (rem >> 4) * 64, n0 = (rem & 15) * 64;
        const float* in = z == 0 ? wq : (z == 1 ? wk : wv);
        bf16_t* out = z == 0 ? wqt : (z == 1 ? wkt : wvt);
        const int r = t >> 2, c0 = (t & 3) * 16;
        #pragma unroll
        for (int j = 0; j < 16; j += 4) {
            float4 v = *(const float4*)&in[(size_t)(k0 + r) * C_ + n0 + c0 + j];
            ts[c0 + j + 0][r] = v.x; ts[c0 + j + 1][r] = v.y;
            ts[c0 + j + 2][r] = v.z; ts[c0 + j + 3][r] = v.w;
        }
        __syncthreads();
        #pragma unroll
        for (int g = 0; g < 2; ++g) {
            bf16x8 o;
            #pragma unroll
            for (int e = 0; e < 8; ++e) o[e] = (bf16_t)ts[r][c0 + g * 8 + e];
            *(bf16x8*)&out[(size_t)(n0 + r) * C_ + k0 + c0 + g * 8] = o;
        }
    } else {
        // zero Mm: 131072 floats over 8 blocks, 64 floats/thread
        float* p = Mm + (size_t)(bid - 4864) * 16384 + (size_t)t * 64;
        float4 z4 = {0.f, 0.f, 0.f, 0.f};
        #pragma unroll
        for (int k = 0; k < 64; k += 4) *(float4*)&p[k] = z4;
    }
}

// -------------------------------------------------------------------------
// Fused QKV projection (R5 epilogue — direct stores; LDS-transpose epilogue
// REGRESSED: 34KB LDS halved occupancy + 8-way bank conflicts, R7).
// z=0: y@wq -> Qt (transposed), z=1: x@wk -> Kb, z=2: y@wv -> Vt (transposed)
// -------------------------------------------------------------------------
__global__ __launch_bounds__(256) void qkv_proj(
    const bf16_t* __restrict__ ybf, const bf16_t* __restrict__ xbf,
    const bf16_t* __restrict__ wqt, const bf16_t* __restrict__ wkt,
    const bf16_t* __restrict__ wvt,
    const float* __restrict__ bq, const float* __restrict__ bk,
    const float* __restrict__ bv,
    bf16_t* __restrict__ Qt, bf16_t* __restrict__ Kb, bf16_t* __restrict__ Vt)
{
    const int z = blockIdx.z;
    const bf16_t* A  = (z == 1) ? xbf : ybf;
    const bf16_t* Bt = (z == 0) ? wqt : (z == 1) ? wkt : wvt;
    const float* bias = (z == 0) ? bq : (z == 1) ? bk : bv;
    const int K = C_;

    __shared__ bf16_t As[128 * 32];
    __shared__ bf16_t Bs[128 * 32];

    const int t = threadIdx.x;
    const int w = t >> 6, lane = t & 63;
    const int wm = (w >> 1) * 64, wn = (w & 1) * 64;
    const int l15 = lane & 15, l4 = lane >> 4;
    const int row0 = blockIdx.y * 128, col0 = blockIdx.x * 128;

    const int sr = t >> 2, sk = (t & 3) * 8;
    const bf16_t* gA = A + (size_t)(row0 + sr) * K + sk;
    const bf16_t* gB = Bt + (size_t)(col0 + sr) * K + sk;
    bf16_t* lA = As + (t & ~63) * 8;
    bf16_t* lB = Bs + (t & ~63) * 8;

    f32x4 acc[4][4] = {};

    for (int k0 = 0; k0 < K; k0 += 32) {
        __syncthreads();
        gload16(gA + k0, lA);
        gload16(gA + k0 + (size_t)64 * K, lA + 2048);
        gload16(gB + k0, lB);
        gload16(gB + k0 + (size_t)64 * K, lB + 2048);
        __syncthreads();
        bf16x8 a[4], b[4];
        #pragma unroll
        for (int i = 0; i < 4; ++i)
            a[i] = *(const bf16x8*)&As[(wm + i * 16 + l15) * 32 + l4 * 8];
        #pragma unroll
        for (int j = 0; j < 4; ++j)
            b[j] = *(const bf16x8*)&Bs[(wn + j * 16 + l15) * 32 + l4 * 8];
        #pragma unroll
        for (int i = 0; i < 4; ++i)
            #pragma unroll
            for (int j = 0; j < 4; ++j)
                acc[i][j] = __builtin_amdgcn_mfma_f32_16x16x32_bf16(
                    a[i], b[j], acc[i][j], 0, 0, 0);
    }

    if (z != 1) {
        bf16_t* To = (z == 0) ? Qt : Vt;
        #pragma unroll
        for (int i = 0; i < 4; ++i) {
            int mb = row0 + wm + i * 16 + l4 * 4;
            int b2 = mb >> 11, s = mb & 2047;
            #pragma unroll
            for (int j = 0; j < 4; ++j) {
                int c = col0 + wn + j * 16 + l15;
                float bv2 = bias[c];
                bf16x4 o;
                #pragma unroll
                for (int r = 0; r < 4; ++r) o[r] = (bf16_t)(acc[i][j][r] + bv2);
                *(bf16x4*)&To[((size_t)b2 * C_ + c) * S_ + s] = o;
            }
        }
    } else {
        #pragma unroll
        for (int i = 0; i < 4; ++i)
            #pragma unroll
            for (int j = 0; j < 4; ++j) {
                int c = col0 + wn + j * 16 + l15;
                float bv2 = bias[c];
                #pragma unroll
                for (int r = 0; r < 4; ++r) {
                    int m = row0 + wm + i * 16 + l4 * 4 + r;
                    Kb[(size_t)m * C_ + c] = (bf16_t)(acc[i][j][r] + bv2);
                }
            }
    }
}

// -------------------------------------------------------------------------
// FUSED cv + qtcv (R5 loop structure).  GRID SWIZZLE: blockIdx.x = bh so
// the 16 heads sharing one t_mat tile dispatch back-to-back -> t_mat reuse
// is temporally clustered into per-XCD L2 instead of 16 spread LLC reads.
// grid (BH=32, S/128=16, P=4) = 2048 blocks, 8 blocks/CU (20 KB LDS).
// -------------------------------------------------------------------------
__global__ __launch_bounds__(256) void cv_qtcv_fused(
    const float* __restrict__ t_mat, const bf16_t* __restrict__ Vt,
    const bf16_t* __restrict__ Qt,
    const float* __restrict__ wc, const float* __restrict__ bc,
    float* __restrict__ Mm)
{
    const int bh = blockIdx.x, b = bh >> 4, h = bh & 15;
    const int q0 = blockIdx.y * 128;
    const int p = blockIdx.z;
    const int t = threadIdx.x;
    const int w = t >> 6, lane = t & 63;
    const int l15 = lane & 15, l4 = lane >> 4;

    __shared__ bf16_t smem[10240];       // 20 KB
    bf16_t* As = smem;                   // 128*32 (8 KB)
    bf16_t* Bs = smem + 4096;            // 2 x 64*32 (8 KB)
    bf16_t* cvs = smem;                  // epilogue: [c][64][40]

    const float LOG2E2 = 2.8853900817779268f;  // 2/ln2
    const float wch2 = wc[h] * LOG2E2, bch2 = bc[h] * LOG2E2;
    const float* tb = t_mat + (size_t)b * S_ * S_ + (size_t)q0 * S_;
    const bf16_t* Vb = Vt + ((size_t)b * C_ + h * 64) * S_;

    const int rr = t >> 1, sp = (t & 1) * 16;
    const int vd = t >> 2, vse = (t & 3) * 8;
    const int lBoff = (t & ~63) * 8;

    f32x4 acc[2][4] = {};

    const int s_beg = p * 512, s_end = s_beg + 512;
    const float* trow = tb + (size_t)rr * S_ + sp;

    float4 v0 = *(const float4*)&trow[s_beg];
    float4 v1 = *(const float4*)&trow[s_beg + 4];
    float4 v2 = *(const float4*)&trow[s_beg + 8];
    float4 v3 = *(const float4*)&trow[s_beg + 12];

    int buf = 0;
    for (int s0 = s_beg; s0 < s_end; s0 += 32, buf ^= 1) {
        bf16x8 p0, p1;
        p0[0] = (bf16_t)tanh_folded(v0.x, wch2, bch2);
        p0[1] = (bf16_t)tanh_folded(v0.y, wch2, bch2);
        p0[2] = (bf16_t)tanh_folded(v0.z, wch2, bch2);
        p0[3] = (bf16_t)tanh_folded(v0.w, wch2, bch2);
        p0[4] = (bf16_t)tanh_folded(v1.x, wch2, bch2);
        p0[5] = (bf16_t)tanh_folded(v1.y, wch2, bch2);
        p0[6] = (bf16_t)tanh_folded(v1.z, wch2, bch2);
        p0[7] = (bf16_t)tanh_folded(v1.w, wch2, bch2);
        p1[0] = (bf16_t)tanh_folded(v2.x, wch2, bch2);
        p1[1] = (bf16_t)tanh_folded(v2.y, wch2, bch2);
        p1[2] = (bf16_t)tanh_folded(v2.z, wch2, bch2);
        p1[3] = (bf16_t)tanh_folded(v2.w, wch2, bch2);
        p1[4] = (bf16_t)tanh_folded(v3.x, wch2, bch2);
        p1[5] = (bf16_t)tanh_folded(v3.y, wch2, bch2);
        p1[6] = (bf16_t)tanh_folded(v3.z, wch2, bch2);
        p1[7] = (bf16_t)tanh_folded(v3.w, wch2, bch2);
        gload16(Vb + (size_t)vd * S_ + s0 + vse, Bs + buf * 2048 + lBoff);
        *(bf16x8*)&As[rr * 32 + sp] = p0;
        *(bf16x8*)&As[rr * 32 + sp + 8] = p1;
        __syncthreads();
        if (s0 + 32 < s_end) {
            const float* nrow = &trow[s0 + 32];
            v0 = *(const float4*)&nrow[0];
            v1 = *(const float4*)&nrow[4];
            v2 = *(const float4*)&nrow[8];
            v3 = *(const float4*)&nrow[12];
        }
        bf16x8 a0 = *(const bf16x8*)&As[(w * 32 + l15) * 32 + l4 * 8];
        bf16x8 a1 = *(const bf16x8*)&As[(w * 32 + 16 + l15) * 32 + l4 * 8];
        #pragma unroll
        for (int j = 0; j < 4; ++j) {
            bf16x8 bb = *(const bf16x8*)&Bs[buf * 2048 + (j * 16 + l15) * 32 + l4 * 8];
            acc[0][j] = __builtin_amdgcn_mfma_f32_16x16x32_bf16(a0, bb, acc[0][j], 0, 0, 0);
            acc[1][j] = __builtin_amdgcn_mfma_f32_16x16x32_bf16(a1, bb, acc[1][j], 0, 0, 0);
        }
    }

    // ---- epilogue: M[d',d] += Qt[d',q] * cv(q,d) over this block's q-tile
    __syncthreads();
    #pragma unroll
    for (int i = 0; i < 2; ++i)
        #pragma unroll
        for (int j = 0; j < 4; ++j) {
            int d = j * 16 + l15;
            bf16x4 o;
            #pragma unroll
            for (int r = 0; r < 4; ++r) o[r] = (bf16_t)acc[i][j][r];
            *(bf16x4*)&cvs[(size_t)w * 2560 + d * 40 + i * 16 + l4 * 4] = o;
        }
    __syncthreads();

    const bf16_t* Qrow = Qt + ((size_t)b * C_ + h * 64 + w * 16 + l15) * S_ + q0 + l4 * 8;
    f32x4 macc[4] = {};
    #pragma unroll
    for (int c = 0; c < 4; ++c) {
        bf16x8 a = *(const bf16x8*)&Qrow[c * 32];
        #pragma unroll
        for (int j = 0; j < 4; ++j) {
            bf16x8 bb = *(const bf16x8*)&cvs[(size_t)c * 2560 + (j * 16 + l15) * 40 + l4 * 8];
            macc[j] = __builtin_amdgcn_mfma_f32_16x16x32_bf16(a, bb, macc[j], 0, 0, 0);
        }
    }

    float* mp = Mm + (size_t)bh * 64 * 64;
    #pragma unroll
    for (int j = 0; j < 4; ++j)
        #pragma unroll
        for (int r = 0; r < 4; ++r)
            atomicAdd(&mp[(size_t)(w * 16 + l4 * 4 + r) * 64 + j * 16 + l15],
                      macc[j][r]);
}

// -------------------------------------------------------------------------
// Wefft[b, co, h*64+d'] = (1/8) * sum_d M[bh,d',d] * wf[h*64+d, co]  (bf16)
// -------------------------------------------------------------------------
__global__ __launch_bounds__(256) void weff_kernel(
    const float* __restrict__ Mm, const float* __restrict__ wf,
    bf16_t* __restrict__ Wefft)
{
    const int b = blockIdx.z, h = blockIdx.y;
    const int co0 = blockIdx.x * 64;
    const int t = threadIdx.x;
    const int tx = t & 15, ty = t >> 4;

    __shared__ float Ms[64][64];
    __shared__ float Ws[64][64];

    const float* Mb = Mm + (size_t)(b * H_ + h) * 64 * 64;

    const int r  = t >> 2;
    const int c4 = (t & 3) << 2;

    #pragma unroll
    for (int rep = 0; rep < 4; ++rep) {
        int col = c4 + rep * 16;
        float4 m4 = *(const float4*)&Mb[(size_t)r * 64 + col];
        Ms[col + 0][r] = m4.x; Ms[col + 1][r] = m4.y;
        Ms[col + 2][r] = m4.z; Ms[col + 3][r] = m4.w;
        float4 w4 = *(const float4*)&wf[(size_t)(h * 64 + r) * C_ + co0 + col];
        *(float4*)&Ws[r][col] = w4;
    }
    __syncthreads();

    float acc[4][4] = {};
    #pragma unroll
    for (int kk = 0; kk < 64; ++kk) {
        float av[4], bv2[4];
        *(float4*)&av[0] = *(const float4*)&Ms[kk][ty * 4];
        *(float4*)&bv2[0] = *(const float4*)&Ws[kk][tx * 4];
        #pragma unroll
        for (int i = 0; i < 4; ++i)
            #pragma unroll
            for (int j = 0; j < 4; ++j)
                acc[i][j] = fmaf(av[i], bv2[j], acc[i][j]);
    }

    bf16_t* wp = Wefft + (size_t)b * C_ * C_;
    #pragma unroll
    for (int i = 0; i < 4; ++i)
        #pragma unroll
        for (int j = 0; j < 4; ++j)
            wp[(size_t)(co0 + tx * 4 + j) * C_ + h * 64 + ty * 4 + i] =
                (bf16_t)(acc[i][j] * 0.125f);  // fold 1/sqrt(D)=1/8
}

// -------------------------------------------------------------------------
// out = mish(Kb[b] @ Wefft[b]^T + bf), fp32 out. 128x64 tiles,
// grid (16, 16, 2) = 512 blocks (2/CU).
// -------------------------------------------------------------------------
__global__ __launch_bounds__(256) void final_gemm(
    const bf16_t* __restrict__ Kb, const bf16_t* __restrict__ Weft,
    const float* __restrict__ bias, float* __restrict__ out)
{
    const int z = blockIdx.z;
    const bf16_t* A  = Kb + (size_t)z * S_ * C_;
    const bf16_t* Bt = Weft + (size_t)z * C_ * C_;
    float* Co = out + (size_t)z * S_ * C_;
    const int K = C_;

    __shared__ bf16_t As[128 * 32];
    __shared__ bf16_t Bs[64 * 32];

    const int t = threadIdx.x;
    const int w = t >> 6, lane = t & 63;
    const int l15 = lane & 15, l4 = lane >> 4;
    const int row0 = blockIdx.y * 128, col0 = blockIdx.x * 64;

    const int sr = t >> 2, sk = (t & 3) * 8;
    const bf16_t* gA = A + (size_t)(row0 + sr) * K + sk;
    const bf16_t* gB = Bt + (size_t)(col0 + sr) * K + sk;
    bf16_t* lA = As + (t & ~63) * 8;
    bf16_t* lB = Bs + (t & ~63) * 8;

    f32x4 acc[2][4] = {};

    for (int k0 = 0; k0 < K; k0 += 32) {
        __syncthreads();
        gload16(gA + k0, lA);
        gload16(gA + k0 + (size_t)64 * K, lA + 2048);
        gload16(gB + k0, lB);
        __syncthreads();
        bf16x8 a0 = *(const bf16x8*)&As[(w * 32 + l15) * 32 + l4 * 8];
        bf16x8 a1 = *(const bf16x8*)&As[(w * 32 + 16 + l15) * 32 + l4 * 8];
        #pragma unroll
        for (int j = 0; j < 4; ++j) {
            bf16x8 bb = *(const bf16x8*)&Bs[(j * 16 + l15) * 32 + l4 * 8];
            acc[0][j] = __builtin_amdgcn_mfma_f32_16x16x32_bf16(a0, bb, acc[0][j], 0, 0, 0);
            acc[1][j] = __builtin_amdgcn_mfma_f32_16x16x32_bf16(a1, bb, acc[1][j], 0, 0, 0);
        }
    }

    #pragma unroll
    for (int i = 0; i < 2; ++i)
        #pragma unroll
        for (int j = 0; j < 4; ++j) {
            int c = col0 + j * 16 + l15;
            float bv2 = bias[c];
            #pragma unroll
            for (int r = 0; r < 4; ++r) {
                int m = row0 + w * 32 + i * 16 + l4 * 4 + r;
                Co[(size_t)m * C_ + c] = mish_f(acc[i][j][r] + bv2);
            }
        }
}

// -------------------------------------------------------------------------
extern "C" void kernel_launch(void* const* d_in, const int* in_sizes, int n_in,
                              void* d_out, int out_size, void* d_ws, size_t ws_size,
                              hipStream_t stream) {
    const float* x     = (const float*)d_in[0];
    const float* y     = (const float*)d_in[1];
    const float* t_mat = (const float*)d_in[2];
    const float* wq    = (const float*)d_in[3];
    const float* bq    = (const float*)d_in[4];
    const float* wk    = (const float*)d_in[5];
    const float* bk    = (const float*)d_in[6];
    const float* wv    = (const float*)d_in[7];
    const float* bv    = (const float*)d_in[8];
    const float* wc    = (const float*)d_in[9];
    const float* bc    = (const float*)d_in[10];
    const float* wf    = (const float*)d_in[11];
    const float* bf    = (const float*)d_in[12];
    float* out = (float*)d_out;

    // workspace layout (byte offsets)
    char* base = (char*)d_ws;
    bf16_t* Qt   = (bf16_t*)(base + 0);          //  8 MiB  [b][c][s]
    bf16_t* Kb   = (bf16_t*)(base + 8388608);    //  8 MiB  [b*s][c]
    bf16_t* Vt   = (bf16_t*)(base + 16777216);   //  8 MiB  [b][c][s]
    float*  Mm   = (float*) (base + 25165824);   //  0.5 MiB
    bf16_t* Weft = (bf16_t*)(base + 25690112);   //  4 MiB  [b][co][cin]
    bf16_t* ybf  = (bf16_t*)(base + 29884416);   //  8 MiB
    bf16_t* xbf  = (bf16_t*)(base + 38273024);   //  8 MiB
    bf16_t* wqt  = (bf16_t*)(base + 46661632);   //  2 MiB
    bf16_t* wkt  = (bf16_t*)(base + 48758784);   //  2 MiB
    bf16_t* wvt  = (bf16_t*)(base + 50855936);   //  2 MiB

    dim3 blk(256);

    // merged conversions + weight transposes + Mm zeroing (4872 blocks)
    prep_kernel<<<dim3(4872), blk, 0, stream>>>(
        y, ybf, x, xbf, wq, wk, wv, wqt, wkt, wvt, Mm);

    // fused QKV projections (768 blocks)
    qkv_proj<<<dim3(C_ / 128, (B_ * S_) / 128, 3), blk, 0, stream>>>(
        ybf, xbf, wqt, wkt, wvt, bq, bk, bv, Qt, Kb, Vt);

    // fused cv + M-accumulation (2048 blocks, bh-fastest swizzle)
    cv_qtcv_fused<<<dim3(B_ * H_, S_ / 128, 4), blk, 0, stream>>>(
        t_mat, Vt, Qt, wc, bc, Mm);

    // Weff^T (bf16), 1/8 folded
    weff_kernel<<<dim3(C_ / 64, H_, B_), blk, 0, stream>>>(Mm, wf, Weft);

    // out = mish(K @ Weff + bf), 512 blocks
    final_gemm<<<dim3(C_ / 64, S_ / 128, B_), blk, 0, stream>>>(
        Kb, Weft, bf, out);
}